// Round 6
// baseline (267.495 us; speedup 1.0000x reference)
//
#include <hip/hip_runtime.h>
#include <stdint.h>

typedef __attribute__((ext_vector_type(4))) float f32x4;
typedef __attribute__((ext_vector_type(8))) short bf16x8;
typedef __attribute__((ext_vector_type(4))) unsigned short u16x4;

constexpr int cB = 4, cS = 4096, cD = 1024, cH = 1024;
constexpr int cM = cB * cS;      // 16384
constexpr int cN = 2 * cH;       // 2048
constexpr int cK = cD;           // 1024
constexpr int NCH = 64;          // scan chunks along S
constexpr int CLEN = cS / NCH;   // 64

__device__ __forceinline__ unsigned short f2bf(float f) {
  union { float f; uint32_t u; } v; v.f = f;
  uint32_t r = v.u + 0x7FFFu + ((v.u >> 16) & 1u);
  return (unsigned short)(r >> 16);
}
__device__ __forceinline__ float bf2f(unsigned short h) {
  union { float f; uint32_t u; } v; v.u = ((uint32_t)h) << 16;
  return v.f;
}

// fp32 -> bf16 round (x and W; residual terms dropped — see error model R5)
__global__ void round_kernel(const float* __restrict__ src,
                             unsigned short* __restrict__ hi) {
  int i = (blockIdx.x * blockDim.x + threadIdx.x) * 4;
  f32x4 x = *(const f32x4*)(src + i);
  u16x4 h;
#pragma unroll
  for (int j = 0; j < 4; ++j) h[j] = f2bf(x[j]);
  *(u16x4*)(hi + i) = h;
}

// ======= GEMM: [16384 x 2048] = x_bf * [Wz;Wh]_bf^T  (pure bf16, R2 structure)
constexpr int BM = 128, BN = 128, BK = 64;

__global__ __launch_bounds__(256, 5) void gemm_kernel(
    const unsigned short* __restrict__ xh,
    const unsigned short* __restrict__ wwh,
    const float* __restrict__ bz, const float* __restrict__ bhv,
    unsigned short* __restrict__ cbuf, unsigned short* __restrict__ gbuf)
{
  __shared__ unsigned short Ah[BM * BK], Bt[BN * BK];   // 16 KiB + 16 KiB
  const int tid  = threadIdx.x;
  const int lane = tid & 63;
  const int wv   = tid >> 6;
  const int wr   = wv >> 1, wc = wv & 1;
  const int nt = blockIdx.x, mt = blockIdx.y;   // nt fastest -> A-strip L2 sharing
  const int m0 = mt * BM, n0 = nt * BN;
  const int fr = lane & 15, fq = lane >> 4;

  f32x4 acc[4][4] = {};

  // staging: LDS linear dest; source pre-swizzled (rule #21): col ^= (row&7)
  const int srow = tid >> 3;                              // 0..31
  const int scol = (((tid & 7) ^ (srow & 7)) << 3);       // bf16 index

  for (int kt = 0; kt < cK / BK; ++kt) {
    const int k0 = kt * BK;
    __syncthreads();
#pragma unroll
    for (int r = 0; r < 4; ++r) {
      const int row = r * 32 + srow;
      const int ldsoff = r * 4096 + tid * 16;
      const unsigned short* ga = xh  + (size_t)(m0 + row) * cK + k0 + scol;
      const unsigned short* gb = wwh + (size_t)(n0 + row) * cK + k0 + scol;
      __builtin_amdgcn_global_load_lds((const __attribute__((address_space(1))) void*)ga,
        (__attribute__((address_space(3))) void*)((char*)Ah + ldsoff), 16, 0, 0);
      __builtin_amdgcn_global_load_lds((const __attribute__((address_space(1))) void*)gb,
        (__attribute__((address_space(3))) void*)((char*)Bt + ldsoff), 16, 0, 0);
    }
    __syncthreads();
#pragma unroll
    for (int kk = 0; kk < BK / 32; ++kk) {
      bf16x8 fa[4], fb[4];
#pragma unroll
      for (int i = 0; i < 4; ++i) {
        const int ar = wr * 64 + i * 16 + fr;
        const int ca = (kk * 64 + fq * 16) ^ ((ar & 7) << 4);   // swizzled read (bytes)
        fa[i] = *(const bf16x8*)((const char*)Ah + ar * 128 + ca);
        const int br = wc * 64 + i * 16 + fr;
        const int cb = (kk * 64 + fq * 16) ^ ((br & 7) << 4);
        fb[i] = *(const bf16x8*)((const char*)Bt + br * 128 + cb);
      }
#pragma unroll
      for (int i = 0; i < 4; ++i)
#pragma unroll
        for (int j = 0; j < 4; ++j)
          acc[i][j] = __builtin_amdgcn_mfma_f32_16x16x32_bf16(fa[i], fb[j], acc[i][j], 0, 0, 0);
    }
  }

  // epilogue: n<1024 -> c = sigmoid(-k); else g = a>=0 ? a+0.5 : sigmoid(a); bf16 out
  const bool is_k = (n0 < cH);
#pragma unroll
  for (int j = 0; j < 4; ++j) {
    const int n = n0 + wc * 64 + j * 16 + fr;
    const float bias = is_k ? bz[n] : bhv[n - cH];
#pragma unroll
    for (int i = 0; i < 4; ++i) {
#pragma unroll
      for (int rg = 0; rg < 4; ++rg) {
        const int m = m0 + wr * 64 + i * 16 + fq * 4 + rg;
        const float val = acc[i][j][rg] + bias;
        if (is_k) {
          cbuf[(size_t)m * cH + n] = f2bf(1.0f / (1.0f + expf(val)));
        } else {
          const float g = (val >= 0.0f) ? (val + 0.5f) : (1.0f / (1.0f + expf(-val)));
          gbuf[(size_t)m * cH + (n - cH)] = f2bf(g);
        }
      }
    }
  }
}

// =================== chunked scan: h_t = c_t*h_{t-1} + (1-c_t)*g_t ============
__global__ void scan_chunk_kernel(const unsigned short* __restrict__ cb,
                                  const unsigned short* __restrict__ gb,
                                  float* __restrict__ Pb, float* __restrict__ Qb) {
  const int bc = blockIdx.x;
  const int b = bc / NCH, ch = bc % NCH;
  const int h4 = threadIdx.x * 4;
  size_t base = ((size_t)b * cS + (size_t)ch * CLEN) * cH + h4;
  f32x4 p = {1.f, 1.f, 1.f, 1.f};
  f32x4 q = {0.f, 0.f, 0.f, 0.f};
#pragma unroll 4
  for (int i = 0; i < CLEN; ++i) {
    u16x4 cv = *(const u16x4*)(cb + base + (size_t)i * cH);
    u16x4 gv = *(const u16x4*)(gb + base + (size_t)i * cH);
#pragma unroll
    for (int j = 0; j < 4; ++j) {
      const float c = bf2f(cv[j]), g = bf2f(gv[j]);
      q[j] = c * q[j] + (1.0f - c) * g;
      p[j] *= c;
    }
  }
  size_t o = ((size_t)b * NCH + ch) * cH + h4;
  *(f32x4*)(Pb + o) = p;
  *(f32x4*)(Qb + o) = q;
}

__global__ void scan_prefix_kernel(const float* __restrict__ h0,
                                   const float* __restrict__ Pb, const float* __restrict__ Qb,
                                   float* __restrict__ hin) {
  const int idx = blockIdx.x * blockDim.x + threadIdx.x;  // b*H+h
  const int b = idx / cH, h = idx % cH;
  float x = h0[idx];
  float hc = (x >= 0.0f) ? (x + 0.5f) : (1.0f / (1.0f + expf(-x)));  // g(h0)
#pragma unroll 4
  for (int j = 0; j < NCH; ++j) {
    size_t o = ((size_t)b * NCH + j) * cH + h;
    hin[o] = hc;
    hc = Qb[o] + Pb[o] * hc;
  }
}

__global__ void scan_write_kernel(const unsigned short* __restrict__ cb,
                                  const unsigned short* __restrict__ gb,
                                  const float* __restrict__ hin, float* __restrict__ out) {
  const int bc = blockIdx.x;
  const int b = bc / NCH, ch = bc % NCH;
  const int h4 = threadIdx.x * 4;
  f32x4 hc = *(const f32x4*)(hin + ((size_t)b * NCH + ch) * cH + h4);
  size_t base = ((size_t)b * cS + (size_t)ch * CLEN) * cH + h4;
#pragma unroll 4
  for (int i = 0; i < CLEN; ++i) {
    u16x4 cv = *(const u16x4*)(cb + base + (size_t)i * cH);
    u16x4 gv = *(const u16x4*)(gb + base + (size_t)i * cH);
#pragma unroll
    for (int j = 0; j < 4; ++j) {
      const float c = bf2f(cv[j]), g = bf2f(gv[j]);
      hc[j] = c * hc[j] + (1.0f - c) * g;
    }
    *(f32x4*)(out + base + (size_t)i * cH) = hc;
  }
  if (ch == NCH - 1) {
    *(f32x4*)(out + (size_t)cM * cH + (size_t)b * cH + h4) = hc;
  }
}

extern "C" void kernel_launch(void* const* d_in, const int* in_sizes, int n_in,
                              void* d_out, int out_size, void* d_ws, size_t ws_size,
                              hipStream_t stream) {
  const float* x   = (const float*)d_in[0];
  const float* h0  = (const float*)d_in[1];
  const float* Wz  = (const float*)d_in[2];
  const float* bz  = (const float*)d_in[3];
  const float* Wh  = (const float*)d_in[4];
  const float* bh  = (const float*)d_in[5];

  char* ws = (char*)d_ws;
  unsigned short* xh   = (unsigned short*)(ws);                         // 32 MiB
  unsigned short* wwh  = (unsigned short*)(ws + (((size_t)32) << 20));  // 4 MiB
  unsigned short* cbuf = (unsigned short*)(ws + (((size_t)40) << 20));  // 32 MiB
  unsigned short* gbuf = (unsigned short*)(ws + (((size_t)72) << 20));  // 32 MiB
  float* Pb   = (float*)(ws + (((size_t)104) << 20));                   // 1 MiB
  float* Qb   = (float*)(ws + (((size_t)105) << 20));                   // 1 MiB
  float* hin  = (float*)(ws + (((size_t)106) << 20));                   // 1 MiB
  float* out  = (float*)d_out;

  round_kernel<<<cM * cK / 1024, 256, 0, stream>>>(x, xh);
  round_kernel<<<cH * cK / 1024, 256, 0, stream>>>(Wz, wwh);
  round_kernel<<<cH * cK / 1024, 256, 0, stream>>>(Wh, wwh + (size_t)cH * cK);
  gemm_kernel<<<dim3(cN / BN, cM / BM), 256, 0, stream>>>(xh, wwh, bz, bh, cbuf, gbuf);
  scan_chunk_kernel<<<cB * NCH, 256, 0, stream>>>(cbuf, gbuf, Pb, Qb);
  scan_prefix_kernel<<<cB * cH / 256, 256, 0, stream>>>(h0, Pb, Qb, hin);
  scan_write_kernel<<<cB * NCH, 256, 0, stream>>>(cbuf, gbuf, hin, out);
}

// Round 7
// 249.634 us; speedup vs baseline: 1.0715x; 1.0715x over previous
//
#include <hip/hip_runtime.h>
#include <stdint.h>

typedef __attribute__((ext_vector_type(4))) float f32x4;
typedef __attribute__((ext_vector_type(8))) short bf16x8;
typedef __attribute__((ext_vector_type(4))) unsigned short u16x4;

constexpr int cB = 4, cS = 4096, cD = 1024, cH = 1024;
constexpr int cM = cB * cS;      // 16384
constexpr int cN = 2 * cH;       // 2048
constexpr int cK = cD;           // 1024
constexpr int NCH = 64;          // scan chunks along S
constexpr int CLEN = cS / NCH;   // 64

__device__ __forceinline__ unsigned short f2bf(float f) {
  union { float f; uint32_t u; } v; v.f = f;
  uint32_t r = v.u + 0x7FFFu + ((v.u >> 16) & 1u);
  return (unsigned short)(r >> 16);
}
__device__ __forceinline__ float bf2f(unsigned short h) {
  union { float f; uint32_t u; } v; v.u = ((uint32_t)h) << 16;
  return v.f;
}

// fp32 -> bf16 round (x and W; residual terms dropped — see error model R5)
__global__ void round_kernel(const float* __restrict__ src,
                             unsigned short* __restrict__ hi) {
  int i = (blockIdx.x * blockDim.x + threadIdx.x) * 4;
  f32x4 x = *(const f32x4*)(src + i);
  u16x4 h;
#pragma unroll
  for (int j = 0; j < 4; ++j) h[j] = f2bf(x[j]);
  *(u16x4*)(hi + i) = h;
}

// ======= GEMM: [16384 x 2048] = x_bf * [Wz;Wh]_bf^T  (pure bf16, R2 structure)
// R7 change: XCD-chunked block mapping — each XCD owns 16 contiguous mt-rows
// so A-strips are fetched into exactly ONE per-XCD L2 (R6: all 8 -> 245 MB).
constexpr int BM = 128, BN = 128, BK = 64;

__global__ __launch_bounds__(256, 5) void gemm_kernel(
    const unsigned short* __restrict__ xh,
    const unsigned short* __restrict__ wwh,
    const float* __restrict__ bz, const float* __restrict__ bhv,
    unsigned short* __restrict__ cbuf, unsigned short* __restrict__ gbuf)
{
  __shared__ unsigned short Ah[BM * BK], Bt[BN * BK];   // 16 KiB + 16 KiB
  const int tid  = threadIdx.x;
  const int lane = tid & 63;
  const int wv   = tid >> 6;
  const int wr   = wv >> 1, wc = wv & 1;

  // XCD-chunked mapping: dispatch round-robins bid%8 across XCDs.
  const int bid = blockIdx.x;          // 0..2047
  const int xcd = bid & 7;
  const int idx = bid >> 3;            // 0..255 within XCD
  const int mt  = xcd * 16 + (idx >> 4);   // 16 mt-rows per XCD, nt-fastest
  const int nt  = idx & 15;
  const int m0 = mt * BM, n0 = nt * BN;
  const int fr = lane & 15, fq = lane >> 4;

  f32x4 acc[4][4] = {};

  // staging: LDS linear dest; source pre-swizzled (rule #21): col ^= (row&7)
  const int srow = tid >> 3;                              // 0..31
  const int scol = (((tid & 7) ^ (srow & 7)) << 3);       // bf16 index

  for (int kt = 0; kt < cK / BK; ++kt) {
    const int k0 = kt * BK;
    __syncthreads();
#pragma unroll
    for (int r = 0; r < 4; ++r) {
      const int row = r * 32 + srow;
      const int ldsoff = r * 4096 + tid * 16;
      const unsigned short* ga = xh  + (size_t)(m0 + row) * cK + k0 + scol;
      const unsigned short* gb = wwh + (size_t)(n0 + row) * cK + k0 + scol;
      __builtin_amdgcn_global_load_lds((const __attribute__((address_space(1))) void*)ga,
        (__attribute__((address_space(3))) void*)((char*)Ah + ldsoff), 16, 0, 0);
      __builtin_amdgcn_global_load_lds((const __attribute__((address_space(1))) void*)gb,
        (__attribute__((address_space(3))) void*)((char*)Bt + ldsoff), 16, 0, 0);
    }
    __syncthreads();
#pragma unroll
    for (int kk = 0; kk < BK / 32; ++kk) {
      bf16x8 fa[4], fb[4];
#pragma unroll
      for (int i = 0; i < 4; ++i) {
        const int ar = wr * 64 + i * 16 + fr;
        const int ca = (kk * 64 + fq * 16) ^ ((ar & 7) << 4);   // swizzled read (bytes)
        fa[i] = *(const bf16x8*)((const char*)Ah + ar * 128 + ca);
        const int br = wc * 64 + i * 16 + fr;
        const int cb = (kk * 64 + fq * 16) ^ ((br & 7) << 4);
        fb[i] = *(const bf16x8*)((const char*)Bt + br * 128 + cb);
      }
#pragma unroll
      for (int i = 0; i < 4; ++i)
#pragma unroll
        for (int j = 0; j < 4; ++j)
          acc[i][j] = __builtin_amdgcn_mfma_f32_16x16x32_bf16(fa[i], fb[j], acc[i][j], 0, 0, 0);
    }
  }

  // epilogue: n<1024 -> c = sigmoid(-k); else g = a>=0 ? a+0.5 : sigmoid(a); bf16 out
  const bool is_k = (n0 < cH);
#pragma unroll
  for (int j = 0; j < 4; ++j) {
    const int n = n0 + wc * 64 + j * 16 + fr;
    const float bias = is_k ? bz[n] : bhv[n - cH];
#pragma unroll
    for (int i = 0; i < 4; ++i) {
#pragma unroll
      for (int rg = 0; rg < 4; ++rg) {
        const int m = m0 + wr * 64 + i * 16 + fq * 4 + rg;
        const float val = acc[i][j][rg] + bias;
        if (is_k) {
          cbuf[(size_t)m * cH + n] = f2bf(1.0f / (1.0f + expf(val)));
        } else {
          const float g = (val >= 0.0f) ? (val + 0.5f) : (1.0f / (1.0f + expf(-val)));
          gbuf[(size_t)m * cH + (n - cH)] = f2bf(g);
        }
      }
    }
  }
}

// =================== chunked scan: h_t = c_t*h_{t-1} + (1-c_t)*g_t ============
__global__ void scan_chunk_kernel(const unsigned short* __restrict__ cb,
                                  const unsigned short* __restrict__ gb,
                                  float* __restrict__ Pb, float* __restrict__ Qb) {
  const int bc = blockIdx.x;
  const int b = bc / NCH, ch = bc % NCH;
  const int h4 = threadIdx.x * 4;
  size_t base = ((size_t)b * cS + (size_t)ch * CLEN) * cH + h4;
  f32x4 p = {1.f, 1.f, 1.f, 1.f};
  f32x4 q = {0.f, 0.f, 0.f, 0.f};
#pragma unroll 4
  for (int i = 0; i < CLEN; ++i) {
    u16x4 cv = *(const u16x4*)(cb + base + (size_t)i * cH);
    u16x4 gv = *(const u16x4*)(gb + base + (size_t)i * cH);
#pragma unroll
    for (int j = 0; j < 4; ++j) {
      const float c = bf2f(cv[j]), g = bf2f(gv[j]);
      q[j] = c * q[j] + (1.0f - c) * g;
      p[j] *= c;
    }
  }
  size_t o = ((size_t)b * NCH + ch) * cH + h4;
  *(f32x4*)(Pb + o) = p;
  *(f32x4*)(Qb + o) = q;
}

__global__ void scan_prefix_kernel(const float* __restrict__ h0,
                                   const float* __restrict__ Pb, const float* __restrict__ Qb,
                                   float* __restrict__ hin) {
  const int idx = blockIdx.x * blockDim.x + threadIdx.x;  // b*H+h
  const int b = idx / cH, h = idx % cH;
  float x = h0[idx];
  float hc = (x >= 0.0f) ? (x + 0.5f) : (1.0f / (1.0f + expf(-x)));  // g(h0)
#pragma unroll 4
  for (int j = 0; j < NCH; ++j) {
    size_t o = ((size_t)b * NCH + j) * cH + h;
    hin[o] = hc;
    hc = Qb[o] + Pb[o] * hc;
  }
}

__global__ void scan_write_kernel(const unsigned short* __restrict__ cb,
                                  const unsigned short* __restrict__ gb,
                                  const float* __restrict__ hin, float* __restrict__ out) {
  const int bc = blockIdx.x;
  const int b = bc / NCH, ch = bc % NCH;
  const int h4 = threadIdx.x * 4;
  f32x4 hc = *(const f32x4*)(hin + ((size_t)b * NCH + ch) * cH + h4);
  size_t base = ((size_t)b * cS + (size_t)ch * CLEN) * cH + h4;
#pragma unroll 4
  for (int i = 0; i < CLEN; ++i) {
    u16x4 cv = *(const u16x4*)(cb + base + (size_t)i * cH);
    u16x4 gv = *(const u16x4*)(gb + base + (size_t)i * cH);
#pragma unroll
    for (int j = 0; j < 4; ++j) {
      const float c = bf2f(cv[j]), g = bf2f(gv[j]);
      hc[j] = c * hc[j] + (1.0f - c) * g;
    }
    *(f32x4*)(out + base + (size_t)i * cH) = hc;
  }
  if (ch == NCH - 1) {
    *(f32x4*)(out + (size_t)cM * cH + (size_t)b * cH + h4) = hc;
  }
}

extern "C" void kernel_launch(void* const* d_in, const int* in_sizes, int n_in,
                              void* d_out, int out_size, void* d_ws, size_t ws_size,
                              hipStream_t stream) {
  const float* x   = (const float*)d_in[0];
  const float* h0  = (const float*)d_in[1];
  const float* Wz  = (const float*)d_in[2];
  const float* bz  = (const float*)d_in[3];
  const float* Wh  = (const float*)d_in[4];
  const float* bh  = (const float*)d_in[5];

  char* ws = (char*)d_ws;
  unsigned short* xh   = (unsigned short*)(ws);                         // 32 MiB
  unsigned short* wwh  = (unsigned short*)(ws + (((size_t)32) << 20));  // 4 MiB
  unsigned short* cbuf = (unsigned short*)(ws + (((size_t)40) << 20));  // 32 MiB
  unsigned short* gbuf = (unsigned short*)(ws + (((size_t)72) << 20));  // 32 MiB
  float* Pb   = (float*)(ws + (((size_t)104) << 20));                   // 1 MiB
  float* Qb   = (float*)(ws + (((size_t)105) << 20));                   // 1 MiB
  float* hin  = (float*)(ws + (((size_t)106) << 20));                   // 1 MiB
  float* out  = (float*)d_out;

  round_kernel<<<cM * cK / 1024, 256, 0, stream>>>(x, xh);
  round_kernel<<<cH * cK / 1024, 256, 0, stream>>>(Wz, wwh);
  round_kernel<<<cH * cK / 1024, 256, 0, stream>>>(Wh, wwh + (size_t)cH * cK);
  gemm_kernel<<<(cM / BM) * (cN / BN), 256, 0, stream>>>(xh, wwh, bz, bh, cbuf, gbuf);
  scan_chunk_kernel<<<cB * NCH, 256, 0, stream>>>(cbuf, gbuf, Pb, Qb);
  scan_prefix_kernel<<<cB * cH / 256, 256, 0, stream>>>(h0, Pb, Qb, hin);
  scan_write_kernel<<<cB * NCH, 256, 0, stream>>>(cbuf, gbuf, hin, out);
}

// Round 8
// 153.815 us; speedup vs baseline: 1.7391x; 1.6229x over previous
//
#include <hip/hip_runtime.h>
#include <stdint.h>

typedef __attribute__((ext_vector_type(4))) float f32x4;
typedef __attribute__((ext_vector_type(8))) short bf16x8;
typedef __attribute__((ext_vector_type(4))) unsigned short u16x4;

constexpr int cB = 4, cS = 4096, cD = 1024, cH = 1024;
constexpr int cM = cB * cS;      // 16384
constexpr int cK = cD;           // 1024
constexpr int NCH = 64;          // scan chunks along S
constexpr int CLEN = cS / NCH;   // 64

__device__ __forceinline__ unsigned short f2bf(float f) {
  union { float f; uint32_t u; } v; v.f = f;
  uint32_t r = v.u + 0x7FFFu + ((v.u >> 16) & 1u);
  return (unsigned short)(r >> 16);
}
__device__ __forceinline__ float bf2f(unsigned short h) {
  union { float f; uint32_t u; } v; v.u = ((uint32_t)h) << 16;
  return v.f;
}

// fp32 -> bf16 round (x and W; residual terms dropped — R5/R6 error model,
// measured absmax 0.0156 vs threshold 0.0619)
__global__ void round_kernel(const float* __restrict__ src,
                             unsigned short* __restrict__ hi) {
  int i = (blockIdx.x * blockDim.x + threadIdx.x) * 4;
  f32x4 x = *(const f32x4*)(src + i);
  u16x4 h;
#pragma unroll
  for (int j = 0; j < 4; ++j) h[j] = f2bf(x[j]);
  *(u16x4*)(hi + i) = h;
}

// ======= fused GEMM: per block, BOTH k = x*Wz^T and a = x*Wh^T for one tile.
// R8 theory: R2's per-iter profile (12 loads, 64 MFMA/wave) measured 44% util;
// here the 2nd MFMA stream is the Wh output instead of a W_lo correction —
// same per-iter cost, half the blocks, all work useful.
constexpr int BM = 128, BN = 128, BK = 64;

__global__ __launch_bounds__(256, 2) void gemm_kernel(
    const unsigned short* __restrict__ xh,
    const unsigned short* __restrict__ wwh,   // [Wz(1024 rows); Wh(1024 rows)]
    const float* __restrict__ bz, const float* __restrict__ bhv,
    unsigned short* __restrict__ cbuf, unsigned short* __restrict__ gbuf)
{
  __shared__ unsigned short Ah[BM * BK], Bz[BN * BK], Bh[BN * BK];  // 48 KiB
  const int tid  = threadIdx.x;
  const int lane = tid & 63;
  const int wv   = tid >> 6;
  const int wr   = wv >> 1, wc = wv & 1;

  // XCD-chunked mapping (R7: cut FETCH 245->83 MB). 1024 blocks, 128/XCD.
  const int bid = blockIdx.x;          // 0..1023
  const int xcd = bid & 7;
  const int idx = bid >> 3;            // 0..127 within XCD
  const int mt  = xcd * 16 + (idx >> 3);   // 16 mt-rows per XCD, nt-fastest
  const int nt  = idx & 7;
  const int m0 = mt * BM, n0 = nt * BN;
  const int fr = lane & 15, fq = lane >> 4;

  f32x4 accz[4][4] = {};
  f32x4 acch[4][4] = {};

  // staging: LDS linear dest; source pre-swizzled (rule #21): col ^= (row&7)
  const int srow = tid >> 3;                              // 0..31
  const int scol = (((tid & 7) ^ (srow & 7)) << 3);       // bf16 index

  const unsigned short* gA = xh  + (size_t)m0 * cK;
  const unsigned short* gZ = wwh + (size_t)n0 * cK;
  const unsigned short* gH = wwh + (size_t)(cH + n0) * cK;

  for (int kt = 0; kt < cK / BK; ++kt) {
    const int k0 = kt * BK;
    __syncthreads();
#pragma unroll
    for (int r = 0; r < 4; ++r) {
      const int row = r * 32 + srow;
      const int ldsoff = r * 4096 + tid * 16;
      const size_t goff = (size_t)row * cK + k0 + scol;
      __builtin_amdgcn_global_load_lds((const __attribute__((address_space(1))) void*)(gA + goff),
        (__attribute__((address_space(3))) void*)((char*)Ah + ldsoff), 16, 0, 0);
      __builtin_amdgcn_global_load_lds((const __attribute__((address_space(1))) void*)(gZ + goff),
        (__attribute__((address_space(3))) void*)((char*)Bz + ldsoff), 16, 0, 0);
      __builtin_amdgcn_global_load_lds((const __attribute__((address_space(1))) void*)(gH + goff),
        (__attribute__((address_space(3))) void*)((char*)Bh + ldsoff), 16, 0, 0);
    }
    __syncthreads();
#pragma unroll
    for (int kk = 0; kk < BK / 32; ++kk) {
      bf16x8 fa[4], fz[4], fh[4];
#pragma unroll
      for (int i = 0; i < 4; ++i) {
        const int ar = wr * 64 + i * 16 + fr;
        const int ca = (kk * 64 + fq * 16) ^ ((ar & 7) << 4);   // swizzled read (bytes)
        fa[i] = *(const bf16x8*)((const char*)Ah + ar * 128 + ca);
        const int br = wc * 64 + i * 16 + fr;
        const int cb = (kk * 64 + fq * 16) ^ ((br & 7) << 4);
        fz[i] = *(const bf16x8*)((const char*)Bz + br * 128 + cb);
        fh[i] = *(const bf16x8*)((const char*)Bh + br * 128 + cb);
      }
#pragma unroll
      for (int i = 0; i < 4; ++i)
#pragma unroll
        for (int j = 0; j < 4; ++j) {
          accz[i][j] = __builtin_amdgcn_mfma_f32_16x16x32_bf16(fa[i], fz[j], accz[i][j], 0, 0, 0);
          acch[i][j] = __builtin_amdgcn_mfma_f32_16x16x32_bf16(fa[i], fh[j], acch[i][j], 0, 0, 0);
        }
    }
  }

  // epilogue: c = sigmoid(-(k)); g = a>=0 ? a+0.5 : sigmoid(a); bf16 out
#pragma unroll
  for (int j = 0; j < 4; ++j) {
    const int n = n0 + wc * 64 + j * 16 + fr;
    const float bz_n = bz[n];
    const float bh_n = bhv[n];
#pragma unroll
    for (int i = 0; i < 4; ++i) {
#pragma unroll
      for (int rg = 0; rg < 4; ++rg) {
        const int m = m0 + wr * 64 + i * 16 + fq * 4 + rg;
        const float kv = accz[i][j][rg] + bz_n;
        const float av = acch[i][j][rg] + bh_n;
        cbuf[(size_t)m * cH + n] = f2bf(1.0f / (1.0f + expf(kv)));
        const float g = (av >= 0.0f) ? (av + 0.5f) : (1.0f / (1.0f + expf(-av)));
        gbuf[(size_t)m * cH + n] = f2bf(g);
      }
    }
  }
}

// =================== chunked scan: h_t = c_t*h_{t-1} + (1-c_t)*g_t ============
__global__ void scan_chunk_kernel(const unsigned short* __restrict__ cb,
                                  const unsigned short* __restrict__ gb,
                                  float* __restrict__ Pb, float* __restrict__ Qb) {
  const int bc = blockIdx.x;
  const int b = bc / NCH, ch = bc % NCH;
  const int h4 = threadIdx.x * 4;
  size_t base = ((size_t)b * cS + (size_t)ch * CLEN) * cH + h4;
  f32x4 p = {1.f, 1.f, 1.f, 1.f};
  f32x4 q = {0.f, 0.f, 0.f, 0.f};
#pragma unroll 4
  for (int i = 0; i < CLEN; ++i) {
    u16x4 cv = *(const u16x4*)(cb + base + (size_t)i * cH);
    u16x4 gv = *(const u16x4*)(gb + base + (size_t)i * cH);
#pragma unroll
    for (int j = 0; j < 4; ++j) {
      const float c = bf2f(cv[j]), g = bf2f(gv[j]);
      q[j] = c * q[j] + (1.0f - c) * g;
      p[j] *= c;
    }
  }
  size_t o = ((size_t)b * NCH + ch) * cH + h4;
  *(f32x4*)(Pb + o) = p;
  *(f32x4*)(Qb + o) = q;
}

__global__ void scan_prefix_kernel(const float* __restrict__ h0,
                                   const float* __restrict__ Pb, const float* __restrict__ Qb,
                                   float* __restrict__ hin) {
  const int idx = blockIdx.x * blockDim.x + threadIdx.x;  // b*H+h
  const int b = idx / cH, h = idx % cH;
  float x = h0[idx];
  float hc = (x >= 0.0f) ? (x + 0.5f) : (1.0f / (1.0f + expf(-x)));  // g(h0)
#pragma unroll 4
  for (int j = 0; j < NCH; ++j) {
    size_t o = ((size_t)b * NCH + j) * cH + h;
    hin[o] = hc;
    hc = Qb[o] + Pb[o] * hc;
  }
}

__global__ void scan_write_kernel(const unsigned short* __restrict__ cb,
                                  const unsigned short* __restrict__ gb,
                                  const float* __restrict__ hin, float* __restrict__ out) {
  const int bc = blockIdx.x;
  const int b = bc / NCH, ch = bc % NCH;
  const int h4 = threadIdx.x * 4;
  f32x4 hc = *(const f32x4*)(hin + ((size_t)b * NCH + ch) * cH + h4);
  size_t base = ((size_t)b * cS + (size_t)ch * CLEN) * cH + h4;
#pragma unroll 4
  for (int i = 0; i < CLEN; ++i) {
    u16x4 cv = *(const u16x4*)(cb + base + (size_t)i * cH);
    u16x4 gv = *(const u16x4*)(gb + base + (size_t)i * cH);
#pragma unroll
    for (int j = 0; j < 4; ++j) {
      const float c = bf2f(cv[j]), g = bf2f(gv[j]);
      hc[j] = c * hc[j] + (1.0f - c) * g;
    }
    *(f32x4*)(out + base + (size_t)i * cH) = hc;
  }
  if (ch == NCH - 1) {
    *(f32x4*)(out + (size_t)cM * cH + (size_t)b * cH + h4) = hc;
  }
}

extern "C" void kernel_launch(void* const* d_in, const int* in_sizes, int n_in,
                              void* d_out, int out_size, void* d_ws, size_t ws_size,
                              hipStream_t stream) {
  const float* x   = (const float*)d_in[0];
  const float* h0  = (const float*)d_in[1];
  const float* Wz  = (const float*)d_in[2];
  const float* bz  = (const float*)d_in[3];
  const float* Wh  = (const float*)d_in[4];
  const float* bh  = (const float*)d_in[5];

  char* ws = (char*)d_ws;
  unsigned short* xh   = (unsigned short*)(ws);                         // 32 MiB
  unsigned short* wwh  = (unsigned short*)(ws + (((size_t)32) << 20));  // 4 MiB
  unsigned short* cbuf = (unsigned short*)(ws + (((size_t)40) << 20));  // 32 MiB
  unsigned short* gbuf = (unsigned short*)(ws + (((size_t)72) << 20));  // 32 MiB
  float* Pb   = (float*)(ws + (((size_t)104) << 20));                   // 1 MiB
  float* Qb   = (float*)(ws + (((size_t)105) << 20));                   // 1 MiB
  float* hin  = (float*)(ws + (((size_t)106) << 20));                   // 1 MiB
  float* out  = (float*)d_out;

  round_kernel<<<cM * cK / 1024, 256, 0, stream>>>(x, xh);
  round_kernel<<<cH * cK / 1024, 256, 0, stream>>>(Wz, wwh);
  round_kernel<<<cH * cK / 1024, 256, 0, stream>>>(Wh, wwh + (size_t)cH * cK);
  gemm_kernel<<<(cM / BM) * (cH / BN), 256, 0, stream>>>(xh, wwh, bz, bh, cbuf, gbuf);
  scan_chunk_kernel<<<cB * NCH, 256, 0, stream>>>(cbuf, gbuf, Pb, Qb);
  scan_prefix_kernel<<<cB * cH / 256, 256, 0, stream>>>(h0, Pb, Qb, hin);
  scan_write_kernel<<<cB * NCH, 256, 0, stream>>>(cbuf, gbuf, hin, out);
}

// Round 9
// 143.965 us; speedup vs baseline: 1.8581x; 1.0684x over previous
//
#include <hip/hip_runtime.h>
#include <stdint.h>

typedef __attribute__((ext_vector_type(4))) float f32x4;
typedef __attribute__((ext_vector_type(8))) short bf16x8;
typedef __attribute__((ext_vector_type(4))) unsigned short u16x4;

constexpr int cB = 4, cS = 4096, cD = 1024, cH = 1024;
constexpr int cM = cB * cS;      // 16384
constexpr int cK = cD;           // 1024
constexpr int NCH = 64;          // scan chunks along S
constexpr int CLEN = cS / NCH;   // 64

__device__ __forceinline__ unsigned short f2bf(float f) {
  union { float f; uint32_t u; } v; v.f = f;
  uint32_t r = v.u + 0x7FFFu + ((v.u >> 16) & 1u);
  return (unsigned short)(r >> 16);
}
__device__ __forceinline__ float bf2f(unsigned short h) {
  union { float f; uint32_t u; } v; v.u = ((uint32_t)h) << 16;
  return v.f;
}

// fp32 -> bf16 round (x and W; residual terms dropped — R5/R6 error model,
// measured absmax 0.0156 vs threshold 0.0619)
__global__ void round_kernel(const float* __restrict__ src,
                             unsigned short* __restrict__ hi) {
  int i = (blockIdx.x * blockDim.x + threadIdx.x) * 4;
  f32x4 x = *(const f32x4*)(src + i);
  u16x4 h;
#pragma unroll
  for (int j = 0; j < 4; ++j) h[j] = f2bf(x[j]);
  *(u16x4*)(hi + i) = h;
}

// ======= fused GEMM + chunk-scan epilogue.
// R8: both k=x*Wz^T and a=x*Wh^T per tile (1308 TF raw, best structure found).
// R9: wave wr owns exactly one 64-row scan chunk -> compose (P,Q) in-register
// (rg-local, shfl_xor over fq, i-local) and write Pb/Qb directly; scan_chunk
// kernel deleted (-64 MB re-read).
constexpr int BM = 128, BN = 128, BK = 64;

__global__ __launch_bounds__(256, 2) void gemm_kernel(
    const unsigned short* __restrict__ xh,
    const unsigned short* __restrict__ wwh,   // [Wz(1024 rows); Wh(1024 rows)]
    const float* __restrict__ bz, const float* __restrict__ bhv,
    unsigned short* __restrict__ cbuf, unsigned short* __restrict__ gbuf,
    float* __restrict__ Pb, float* __restrict__ Qb)
{
  __shared__ unsigned short Ah[BM * BK], Bz[BN * BK], Bh[BN * BK];  // 48 KiB
  const int tid  = threadIdx.x;
  const int lane = tid & 63;
  const int wv   = tid >> 6;
  const int wr   = wv >> 1, wc = wv & 1;

  // XCD-chunked mapping (R7: FETCH 245->83 MB). 1024 blocks, 128/XCD.
  const int bid = blockIdx.x;          // 0..1023
  const int xcd = bid & 7;
  const int idx = bid >> 3;            // 0..127 within XCD
  const int mt  = xcd * 16 + (idx >> 3);   // 16 mt-rows per XCD, nt-fastest
  const int nt  = idx & 7;
  const int m0 = mt * BM, n0 = nt * BN;
  const int fr = lane & 15, fq = lane >> 4;

  f32x4 accz[4][4] = {};
  f32x4 acch[4][4] = {};

  // staging: LDS linear dest; source pre-swizzled (rule #21): col ^= (row&7)
  const int srow = tid >> 3;                              // 0..31
  const int scol = (((tid & 7) ^ (srow & 7)) << 3);       // bf16 index

  const unsigned short* gA = xh  + (size_t)m0 * cK;
  const unsigned short* gZ = wwh + (size_t)n0 * cK;
  const unsigned short* gH = wwh + (size_t)(cH + n0) * cK;

  for (int kt = 0; kt < cK / BK; ++kt) {
    const int k0 = kt * BK;
    __syncthreads();
#pragma unroll
    for (int r = 0; r < 4; ++r) {
      const int row = r * 32 + srow;
      const int ldsoff = r * 4096 + tid * 16;
      const size_t goff = (size_t)row * cK + k0 + scol;
      __builtin_amdgcn_global_load_lds((const __attribute__((address_space(1))) void*)(gA + goff),
        (__attribute__((address_space(3))) void*)((char*)Ah + ldsoff), 16, 0, 0);
      __builtin_amdgcn_global_load_lds((const __attribute__((address_space(1))) void*)(gZ + goff),
        (__attribute__((address_space(3))) void*)((char*)Bz + ldsoff), 16, 0, 0);
      __builtin_amdgcn_global_load_lds((const __attribute__((address_space(1))) void*)(gH + goff),
        (__attribute__((address_space(3))) void*)((char*)Bh + ldsoff), 16, 0, 0);
    }
    __syncthreads();
#pragma unroll
    for (int kk = 0; kk < BK / 32; ++kk) {
      bf16x8 fa[4], fz[4], fh[4];
#pragma unroll
      for (int i = 0; i < 4; ++i) {
        const int ar = wr * 64 + i * 16 + fr;
        const int ca = (kk * 64 + fq * 16) ^ ((ar & 7) << 4);   // swizzled read (bytes)
        fa[i] = *(const bf16x8*)((const char*)Ah + ar * 128 + ca);
        const int br = wc * 64 + i * 16 + fr;
        const int cb = (kk * 64 + fq * 16) ^ ((br & 7) << 4);
        fz[i] = *(const bf16x8*)((const char*)Bz + br * 128 + cb);
        fh[i] = *(const bf16x8*)((const char*)Bh + br * 128 + cb);
      }
#pragma unroll
      for (int i = 0; i < 4; ++i)
#pragma unroll
        for (int j = 0; j < 4; ++j) {
          accz[i][j] = __builtin_amdgcn_mfma_f32_16x16x32_bf16(fa[i], fz[j], accz[i][j], 0, 0, 0);
          acch[i][j] = __builtin_amdgcn_mfma_f32_16x16x32_bf16(fa[i], fh[j], acch[i][j], 0, 0, 0);
        }
    }
  }

  // ===== epilogue: c/g + in-register chunk scan.
  // wave wr owns chunk ch = (mt&31)*2 + wr of batch b = mt>>5;
  // row-in-chunk t = i*16 + fq*4 + rg (i,rg reg dims, fq lane dim).
  const int b  = mt >> 5;
  const int ch = (mt & 31) * 2 + wr;
#pragma unroll
  for (int j = 0; j < 4; ++j) {
    const int n = n0 + wc * 64 + j * 16 + fr;
    const float bz_n = bz[n];
    const float bh_n = bhv[n];
    float psg[4], qsg[4];
#pragma unroll
    for (int i = 0; i < 4; ++i) {
      float p = 1.0f, q = 0.0f;
#pragma unroll
      for (int rg = 0; rg < 4; ++rg) {
        const int m = m0 + wr * 64 + i * 16 + fq * 4 + rg;
        const float kv = accz[i][j][rg] + bz_n;
        const float av = acch[i][j][rg] + bh_n;
        const float c = 1.0f / (1.0f + expf(kv));
        const float g = (av >= 0.0f) ? (av + 0.5f) : (1.0f / (1.0f + expf(-av)));
        cbuf[(size_t)m * cH + n] = f2bf(c);
        gbuf[(size_t)m * cH + n] = f2bf(g);
        q = c * q + (1.0f - c) * g;   // compose step (c,(1-c)g) ∘ (p,q)
        p = c * p;
      }
      // cross-fq ordered compose (lanes fq*16+fr; partner masks 16,32)
      float pp = __shfl_xor(p, 16), qq = __shfl_xor(q, 16);
      if (fq & 1) { q = q + p * qq; } else { q = qq + pp * q; }
      p = p * pp;
      pp = __shfl_xor(p, 32); qq = __shfl_xor(q, 32);
      if (fq & 2) { q = q + p * qq; } else { q = qq + pp * q; }
      p = p * pp;
      psg[i] = p; qsg[i] = q;
    }
    float P = psg[0], Q = qsg[0];
#pragma unroll
    for (int i = 1; i < 4; ++i) { Q = qsg[i] + psg[i] * Q; P = psg[i] * P; }
    if (fq == 0) {
      const size_t o = ((size_t)b * NCH + ch) * cH + n;
      Pb[o] = P; Qb[o] = Q;
    }
  }
}

// =================== scan tail ===============================================
__global__ void scan_prefix_kernel(const float* __restrict__ h0,
                                   const float* __restrict__ Pb, const float* __restrict__ Qb,
                                   float* __restrict__ hin) {
  const int idx = blockIdx.x * blockDim.x + threadIdx.x;  // b*H+h
  const int b = idx / cH, h = idx % cH;
  float x = h0[idx];
  float hc = (x >= 0.0f) ? (x + 0.5f) : (1.0f / (1.0f + expf(-x)));  // g(h0)
#pragma unroll 4
  for (int j = 0; j < NCH; ++j) {
    size_t o = ((size_t)b * NCH + j) * cH + h;
    hin[o] = hc;
    hc = Qb[o] + Pb[o] * hc;
  }
}

__global__ void scan_write_kernel(const unsigned short* __restrict__ cb,
                                  const unsigned short* __restrict__ gb,
                                  const float* __restrict__ hin, float* __restrict__ out) {
  const int bc = blockIdx.x;
  const int b = bc / NCH, ch = bc % NCH;
  const int h4 = threadIdx.x * 4;
  f32x4 hc = *(const f32x4*)(hin + ((size_t)b * NCH + ch) * cH + h4);
  size_t base = ((size_t)b * cS + (size_t)ch * CLEN) * cH + h4;
#pragma unroll 4
  for (int i = 0; i < CLEN; ++i) {
    u16x4 cv = *(const u16x4*)(cb + base + (size_t)i * cH);
    u16x4 gv = *(const u16x4*)(gb + base + (size_t)i * cH);
#pragma unroll
    for (int j = 0; j < 4; ++j) {
      const float c = bf2f(cv[j]), g = bf2f(gv[j]);
      hc[j] = c * hc[j] + (1.0f - c) * g;
    }
    *(f32x4*)(out + base + (size_t)i * cH) = hc;
  }
  if (ch == NCH - 1) {
    *(f32x4*)(out + (size_t)cM * cH + (size_t)b * cH + h4) = hc;
  }
}

extern "C" void kernel_launch(void* const* d_in, const int* in_sizes, int n_in,
                              void* d_out, int out_size, void* d_ws, size_t ws_size,
                              hipStream_t stream) {
  const float* x   = (const float*)d_in[0];
  const float* h0  = (const float*)d_in[1];
  const float* Wz  = (const float*)d_in[2];
  const float* bz  = (const float*)d_in[3];
  const float* Wh  = (const float*)d_in[4];
  const float* bh  = (const float*)d_in[5];

  char* ws = (char*)d_ws;
  unsigned short* xh   = (unsigned short*)(ws);                         // 32 MiB
  unsigned short* wwh  = (unsigned short*)(ws + (((size_t)32) << 20));  // 4 MiB
  unsigned short* cbuf = (unsigned short*)(ws + (((size_t)40) << 20));  // 32 MiB
  unsigned short* gbuf = (unsigned short*)(ws + (((size_t)72) << 20));  // 32 MiB
  float* Pb   = (float*)(ws + (((size_t)104) << 20));                   // 1 MiB
  float* Qb   = (float*)(ws + (((size_t)105) << 20));                   // 1 MiB
  float* hin  = (float*)(ws + (((size_t)106) << 20));                   // 1 MiB
  float* out  = (float*)d_out;

  round_kernel<<<cM * cK / 1024, 256, 0, stream>>>(x, xh);
  round_kernel<<<cH * cK / 1024, 256, 0, stream>>>(Wz, wwh);
  round_kernel<<<cH * cK / 1024, 256, 0, stream>>>(Wh, wwh + (size_t)cH * cK);
  gemm_kernel<<<(cM / BM) * (cH / BN), 256, 0, stream>>>(xh, wwh, bz, bh, cbuf, gbuf, Pb, Qb);
  scan_prefix_kernel<<<cB * cH / 256, 256, 0, stream>>>(h0, Pb, Qb, hin);
  scan_write_kernel<<<cB * NCH, 256, 0, stream>>>(cbuf, gbuf, hin, out);
}

// Round 10
// 141.089 us; speedup vs baseline: 1.8959x; 1.0204x over previous
//
#include <hip/hip_runtime.h>
#include <stdint.h>

typedef __attribute__((ext_vector_type(4))) float f32x4;
typedef __attribute__((ext_vector_type(8))) short bf16x8;
typedef __attribute__((ext_vector_type(4))) unsigned short u16x4;
typedef __attribute__((ext_vector_type(4))) unsigned int u32x4;

constexpr int cB = 4, cS = 4096, cD = 1024, cH = 1024;
constexpr int cM = cB * cS;      // 16384
constexpr int cK = cD;           // 1024
constexpr int NCH = 64;          // scan chunks along S
constexpr int CLEN = cS / NCH;   // 64

__device__ __forceinline__ unsigned short f2bf(float f) {
  union { float f; uint32_t u; } v; v.f = f;
  uint32_t r = v.u + 0x7FFFu + ((v.u >> 16) & 1u);
  return (unsigned short)(r >> 16);
}
__device__ __forceinline__ float bf2f(unsigned short h) {
  union { float f; uint32_t u; } v; v.u = ((uint32_t)h) << 16;
  return v.f;
}

// fp32 -> bf16 round (x and W; residual terms dropped — R5/R6 error model,
// measured absmax 0.0156 vs threshold 0.0619)
__global__ void round_kernel(const float* __restrict__ src,
                             unsigned short* __restrict__ hi) {
  int i = (blockIdx.x * blockDim.x + threadIdx.x) * 4;
  f32x4 x = *(const f32x4*)(src + i);
  u16x4 h;
#pragma unroll
  for (int j = 0; j < 4; ++j) h[j] = f2bf(x[j]);
  *(u16x4*)(hi + i) = h;
}

// ======= fused GEMM + chunk-scan epilogue.
// R8: both k=x*Wz^T and a=x*Wh^T per tile. R9: in-register chunk (P,Q).
// R10: pack (c,g) into one u32 per element -> full 64B-sector writes
// (R9 WRITE_SIZE was 147MB for 66MB logical = partial-sector 2x).
constexpr int BM = 128, BN = 128, BK = 64;

__global__ __launch_bounds__(256, 2) void gemm_kernel(
    const unsigned short* __restrict__ xh,
    const unsigned short* __restrict__ wwh,   // [Wz(1024 rows); Wh(1024 rows)]
    const float* __restrict__ bz, const float* __restrict__ bhv,
    unsigned int* __restrict__ cgbuf,
    float* __restrict__ Pb, float* __restrict__ Qb)
{
  __shared__ unsigned short Ah[BM * BK], Bz[BN * BK], Bh[BN * BK];  // 48 KiB
  const int tid  = threadIdx.x;
  const int lane = tid & 63;
  const int wv   = tid >> 6;
  const int wr   = wv >> 1, wc = wv & 1;

  // XCD-chunked mapping (R7: FETCH 245->83 MB). 1024 blocks, 128/XCD.
  const int bid = blockIdx.x;          // 0..1023
  const int xcd = bid & 7;
  const int idx = bid >> 3;            // 0..127 within XCD
  const int mt  = xcd * 16 + (idx >> 3);   // 16 mt-rows per XCD, nt-fastest
  const int nt  = idx & 7;
  const int m0 = mt * BM, n0 = nt * BN;
  const int fr = lane & 15, fq = lane >> 4;

  f32x4 accz[4][4] = {};
  f32x4 acch[4][4] = {};

  // staging: LDS linear dest; source pre-swizzled (rule #21): col ^= (row&7)
  const int srow = tid >> 3;                              // 0..31
  const int scol = (((tid & 7) ^ (srow & 7)) << 3);       // bf16 index

  const unsigned short* gA = xh  + (size_t)m0 * cK;
  const unsigned short* gZ = wwh + (size_t)n0 * cK;
  const unsigned short* gH = wwh + (size_t)(cH + n0) * cK;

  for (int kt = 0; kt < cK / BK; ++kt) {
    const int k0 = kt * BK;
    __syncthreads();
#pragma unroll
    for (int r = 0; r < 4; ++r) {
      const int row = r * 32 + srow;
      const int ldsoff = r * 4096 + tid * 16;
      const size_t goff = (size_t)row * cK + k0 + scol;
      __builtin_amdgcn_global_load_lds((const __attribute__((address_space(1))) void*)(gA + goff),
        (__attribute__((address_space(3))) void*)((char*)Ah + ldsoff), 16, 0, 0);
      __builtin_amdgcn_global_load_lds((const __attribute__((address_space(1))) void*)(gZ + goff),
        (__attribute__((address_space(3))) void*)((char*)Bz + ldsoff), 16, 0, 0);
      __builtin_amdgcn_global_load_lds((const __attribute__((address_space(1))) void*)(gH + goff),
        (__attribute__((address_space(3))) void*)((char*)Bh + ldsoff), 16, 0, 0);
    }
    __syncthreads();
#pragma unroll
    for (int kk = 0; kk < BK / 32; ++kk) {
      bf16x8 fa[4], fz[4], fh[4];
#pragma unroll
      for (int i = 0; i < 4; ++i) {
        const int ar = wr * 64 + i * 16 + fr;
        const int ca = (kk * 64 + fq * 16) ^ ((ar & 7) << 4);   // swizzled read (bytes)
        fa[i] = *(const bf16x8*)((const char*)Ah + ar * 128 + ca);
        const int br = wc * 64 + i * 16 + fr;
        const int cb = (kk * 64 + fq * 16) ^ ((br & 7) << 4);
        fz[i] = *(const bf16x8*)((const char*)Bz + br * 128 + cb);
        fh[i] = *(const bf16x8*)((const char*)Bh + br * 128 + cb);
      }
#pragma unroll
      for (int i = 0; i < 4; ++i)
#pragma unroll
        for (int j = 0; j < 4; ++j) {
          accz[i][j] = __builtin_amdgcn_mfma_f32_16x16x32_bf16(fa[i], fz[j], accz[i][j], 0, 0, 0);
          acch[i][j] = __builtin_amdgcn_mfma_f32_16x16x32_bf16(fa[i], fh[j], acch[i][j], 0, 0, 0);
        }
    }
  }

  // ===== epilogue: packed c/g + in-register chunk scan.
  // wave wr owns chunk ch = (mt&31)*2 + wr of batch b = mt>>5;
  // row-in-chunk t = i*16 + fq*4 + rg.
  const int b  = mt >> 5;
  const int ch = (mt & 31) * 2 + wr;
#pragma unroll
  for (int j = 0; j < 4; ++j) {
    const int n = n0 + wc * 64 + j * 16 + fr;
    const float bz_n = bz[n];
    const float bh_n = bhv[n];
    float psg[4], qsg[4];
#pragma unroll
    for (int i = 0; i < 4; ++i) {
      float p = 1.0f, q = 0.0f;
#pragma unroll
      for (int rg = 0; rg < 4; ++rg) {
        const int m = m0 + wr * 64 + i * 16 + fq * 4 + rg;
        const float kv = accz[i][j][rg] + bz_n;
        const float av = acch[i][j][rg] + bh_n;
        const float c = 1.0f / (1.0f + expf(kv));
        const float g = (av >= 0.0f) ? (av + 0.5f) : (1.0f / (1.0f + expf(-av)));
        cgbuf[(size_t)m * cH + n] = ((uint32_t)f2bf(g) << 16) | (uint32_t)f2bf(c);
        q = c * q + (1.0f - c) * g;   // compose step (c,(1-c)g) ∘ (p,q)
        p = c * p;
      }
      // cross-fq ordered compose (lanes fq*16+fr; partner masks 16,32)
      float pp = __shfl_xor(p, 16), qq = __shfl_xor(q, 16);
      if (fq & 1) { q = q + p * qq; } else { q = qq + pp * q; }
      p = p * pp;
      pp = __shfl_xor(p, 32); qq = __shfl_xor(q, 32);
      if (fq & 2) { q = q + p * qq; } else { q = qq + pp * q; }
      p = p * pp;
      psg[i] = p; qsg[i] = q;
    }
    float P = psg[0], Q = qsg[0];
#pragma unroll
    for (int i = 1; i < 4; ++i) { Q = qsg[i] + psg[i] * Q; P = psg[i] * P; }
    if (fq == 0) {
      const size_t o = ((size_t)b * NCH + ch) * cH + n;
      Pb[o] = P; Qb[o] = Q;
    }
  }
}

// ======= wave-parallel chunk-prefix: Kogge-Stone compose-scan over 64 chunks.
// One wave per (b,h); lane = chunk index. Replaces 64-step serial loop on a
// near-idle chip (R9: 16 blocks) with 1024 blocks of 6-step shfl scans.
__global__ void scan_prefix_kernel(const float* __restrict__ h0,
                                   const float* __restrict__ Pb, const float* __restrict__ Qb,
                                   float* __restrict__ hin) {
  const int wid  = (blockIdx.x * blockDim.x + threadIdx.x) >> 6;  // 0..4095
  const int lane = threadIdx.x & 63;
  const int b = wid >> 10, h = wid & 1023;
  const size_t o = ((size_t)b * NCH + lane) * cH + h;
  float P = Pb[o], Q = Qb[o];
  // inclusive scan: lane L ends with A_L ∘ ... ∘ A_0
#pragma unroll
  for (int off = 1; off < 64; off <<= 1) {
    float Po = __shfl_up(P, off), Qo = __shfl_up(Q, off);
    if (lane >= off) { Q = P * Qo + Q; P = P * Po; }
  }
  // exclusive shift: lane L needs S_{L-1}
  float Pe = __shfl_up(P, 1), Qe = __shfl_up(Q, 1);
  if (lane == 0) { Pe = 1.0f; Qe = 0.0f; }
  const float x = h0[b * cH + h];
  const float h0g = (x >= 0.0f) ? (x + 0.5f) : (1.0f / (1.0f + expf(-x)));  // g(h0)
  hin[o] = Pe * h0g + Qe;
}

__global__ void scan_write_kernel(const unsigned int* __restrict__ cg,
                                  const float* __restrict__ hin, float* __restrict__ out) {
  const int bc = blockIdx.x;
  const int b = bc / NCH, ch = bc % NCH;
  const int h4 = threadIdx.x * 4;
  f32x4 hc = *(const f32x4*)(hin + ((size_t)b * NCH + ch) * cH + h4);
  size_t base = ((size_t)b * cS + (size_t)ch * CLEN) * cH + h4;
#pragma unroll 4
  for (int i = 0; i < CLEN; ++i) {
    u32x4 v = *(const u32x4*)(cg + base + (size_t)i * cH);
#pragma unroll
    for (int j = 0; j < 4; ++j) {
      const float c = bf2f((unsigned short)(v[j] & 0xFFFFu));
      const float g = bf2f((unsigned short)(v[j] >> 16));
      hc[j] = c * hc[j] + (1.0f - c) * g;
    }
    *(f32x4*)(out + base + (size_t)i * cH) = hc;
  }
  if (ch == NCH - 1) {
    *(f32x4*)(out + (size_t)cM * cH + (size_t)b * cH + h4) = hc;
  }
}

extern "C" void kernel_launch(void* const* d_in, const int* in_sizes, int n_in,
                              void* d_out, int out_size, void* d_ws, size_t ws_size,
                              hipStream_t stream) {
  const float* x   = (const float*)d_in[0];
  const float* h0  = (const float*)d_in[1];
  const float* Wz  = (const float*)d_in[2];
  const float* bz  = (const float*)d_in[3];
  const float* Wh  = (const float*)d_in[4];
  const float* bh  = (const float*)d_in[5];

  char* ws = (char*)d_ws;
  unsigned short* xh   = (unsigned short*)(ws);                         // 32 MiB
  unsigned short* wwh  = (unsigned short*)(ws + (((size_t)32) << 20));  // 4 MiB
  unsigned int*   cgbuf= (unsigned int*)(ws + (((size_t)40) << 20));    // 64 MiB
  float* Pb   = (float*)(ws + (((size_t)104) << 20));                   // 1 MiB
  float* Qb   = (float*)(ws + (((size_t)105) << 20));                   // 1 MiB
  float* hin  = (float*)(ws + (((size_t)106) << 20));                   // 1 MiB
  float* out  = (float*)d_out;

  round_kernel<<<cM * cK / 1024, 256, 0, stream>>>(x, xh);
  round_kernel<<<cH * cK / 1024, 256, 0, stream>>>(Wz, wwh);
  round_kernel<<<cH * cK / 1024, 256, 0, stream>>>(Wh, wwh + (size_t)cH * cK);
  gemm_kernel<<<(cM / BM) * (cH / BN), 256, 0, stream>>>(xh, wwh, bz, bh, cgbuf, Pb, Qb);
  scan_prefix_kernel<<<cB * cH * 64 / 256, 256, 0, stream>>>(h0, Pb, Qb, hin);
  scan_write_kernel<<<cB * NCH, 256, 0, stream>>>(cgbuf, hin, out);
}